// Round 6
// baseline (188.538 us; speedup 1.0000x reference)
//
#include <hip/hip_runtime.h>

// CRF NLL on MI355X — round 6: max-TLP chain (1 chain/wave, 8 waves/SIMD).
//
// partition_b = log( a0 . (prod_t M_t) . exp(end) ),  M_t = ET . diag(ee_t).
// 32 chunks x 32 matrices per batch; ONE chunk chain per wave (16384 waves),
// 4-wave blocks with 8 KiB LDS, launch_bounds(256,8) -> 32 waves/CU (~100%
// occupancy): hardware wave interleaving hides the MFMA->pack->MFMA stalls
// that compiler-scheduled 4-chain ILP (r5) could not.
// PI-aligned step (C/D reg order == next B operand order; zero cross-lane)
// kept verbatim from r4/r5. Chunks 0..15 forward products, 16..31 transposed
// (r4-verified) so the combine runs two 16-step vector chains that meet in
// LDS. Path score fused. Fixed 2^-7 per-matrix scaling (exact; napp*7ln2).
//
// ws: [0,32MiB) fragments (512 dw per (b,c)); then msum[512], score[512],
//     napp[512*32].

typedef __attribute__((ext_vector_type(8)))  short    short8;
typedef __attribute__((ext_vector_type(16))) float    f32x16;
typedef __attribute__((ext_vector_type(4)))  unsigned uint4v;

#define S_N 1024
#define T_N 32
#define B_N 512
#define L_CH 32
#define C_CH 32
#define SCALE_MUL 0.0078125f           // 2^-7 folded into ee
#define SCALE_LOG 4.852030263919617f   // 7*ln2 per applied matrix

#define WS_FRAG_DW ((size_t)B_N * C_CH * 512)          // 32 MiB
#define WS_MSUM_OFF (WS_FRAG_DW)
#define WS_SCORE_OFF (WS_FRAG_DW + 512)
#define WS_NAPP_OFF (WS_FRAG_DW + 1024)

#if __has_builtin(__builtin_amdgcn_cvt_pk_bf16_f32)
typedef __attribute__((ext_vector_type(2))) __bf16 bf16x2;
__device__ __forceinline__ unsigned cvtpk(float lo, float hi) {
    return __builtin_bit_cast(unsigned, __builtin_amdgcn_cvt_pk_bf16_f32(lo, hi));
}
#else
__device__ __forceinline__ unsigned cvtpk(float lo, float hi) {
    const unsigned a = __float_as_uint(lo) + 0x8000u;
    const unsigned b = __float_as_uint(hi) + 0x8000u;
    return __builtin_amdgcn_perm(b, a, 0x07060302u);
}
#endif

__device__ __forceinline__ short8 mk8(const unsigned* a) {
    uint4v u = {a[0], a[1], a[2], a[3]};
    return __builtin_bit_cast(short8, u);
}
__device__ __forceinline__ float bflo(unsigned u) { return __uint_as_float(u << 16); }
__device__ __forceinline__ float bfhi(unsigned u) { return __uint_as_float(u & 0xFFFF0000u); }
// PI: involution swapping rows 4-7<->8-11 and 20-23<->24-27
__device__ __forceinline__ int PIx(int x) { return (x & ~12) | ((x & 4) << 1) | ((x & 8) >> 1); }

__global__ __launch_bounds__(256, 8) void crf_chunk(
    const float* __restrict__ em, const int* __restrict__ tags,
    const float* __restrict__ mask, const float* __restrict__ trans,
    const float* __restrict__ startT, unsigned* __restrict__ wsf,
    float* __restrict__ wsflt)
{
    __shared__ unsigned elds[4][512];      // 8 KiB total; per-wave private
    const int wib  = threadIdx.x >> 6;
    const int lane = threadIdx.x & 63;
    const int n    = lane & 31;
    const int h    = lane >> 5;
    const int b    = blockIdx.x >> 3;
    const int c    = (blockIdx.x & 7) * 4 + wib;

    unsigned* my = elds[wib];
    const float* eb = em + ((size_t)b * S_N + c * L_CH) * T_N;

    // ---- stage packed scales: dword (r, m) = bf16x2(ee[r][base], ee[r][base+1])
    #pragma unroll
    for (int i = 0; i < 8; ++i) {
        const int flat = i * 64 + lane;
        const int r = flat >> 4, m = flat & 15;
        const int base = ((m & 4) << 2) + ((m & 2) << 2) + ((m & 1) << 1) + ((m >> 3) << 2);
        const float2 v = *(const float2*)(eb + r * 32 + base);
        my[r * 16 + m] = cvtpk(__expf(v.x) * SCALE_MUL, __expf(v.y) * SCALE_MUL);
    }

    // ---- mask ballot (positions c*32+n; halves duplicate -> low 32 bits) ----
    const int s = c * L_CH + n;
    const float mv = mask[b * S_N + s];
    unsigned mbits = (unsigned)__ballot(mv != 0.0f);
    if (c == 0) mbits &= ~1u;

    // ---- fused path-score partial (h==0 half owns the 32 positions) ----
    {
        const int tc = tags[b * S_N + s];
        int tp = __shfl_up(tc, 1, 32);
        if (n == 0 && c > 0) tp = tags[b * S_N + s - 1];
        float val, ms = mv;
        if (s == 0) val = startT[tc] + eb[tc];
        else        val = mv * (em[((size_t)b * S_N + s) * T_N + tc] + trans[tp * 32 + tc]);
        if (h) { val = 0.f; ms = 0.f; }
        #pragma unroll
        for (int d = 32; d > 0; d >>= 1) {
            val += __shfl_xor(val, d, 64);
            ms  += __shfl_xor(ms,  d, 64);
        }
        if (lane == 0) {
            atomicAdd(&wsflt[WS_SCORE_OFF + b], val);
            atomicAdd(&wsflt[WS_MSUM_OFF + b], ms);
            wsflt[WS_NAPP_OFF + b * C_CH + c] = (float)__popc(mbits);
        }
    }
    // no __syncthreads: each wave reads only the LDS quarter it wrote.

    const bool fwdDir = (c < 16);
    const f32x16 Zacc = {};

    // ---- loop-invariant A fragments (PI-permuted), fwd: ET cols; bwd: ET^T
    unsigned A1[4], A2[4];
    #pragma unroll
    for (int j = 0; j < 4; ++j) {
        const int k1 = PIx(8 * h + 2 * j);
        const int k2 = PIx(16 + 8 * h + 2 * j);
        if (fwdDir) {
            A1[j] = cvtpk(__expf(trans[n * 32 + k1]), __expf(trans[n * 32 + k1 + 1]));
            A2[j] = cvtpk(__expf(trans[n * 32 + k2]), __expf(trans[n * 32 + k2 + 1]));
        } else {
            A1[j] = cvtpk(__expf(trans[k1 * 32 + n]), __expf(trans[(k1 + 1) * 32 + n]));
            A2[j] = cvtpk(__expf(trans[k2 * 32 + n]), __expf(trans[(k2 + 1) * 32 + n]));
        }
    }
    const short8 A1v = mk8(A1), A2v = mk8(A2);
    const bool clean = ((mbits | (c == 0 ? 1u : 0u)) == 0xFFFFFFFFu);
    unsigned* dst = wsf + ((size_t)(b * C_CH + c) * 64 + lane) * 8;

    if (fwdDir) {
        f32x16 D;
        #pragma unroll
        for (int i = 0; i < 16; ++i) {
            const int row = (i & 3) + 8 * (i >> 2) + 4 * h;
            D[i] = (row == n) ? 1.0f : 0.0f;
        }
        #define STEPF(r_) { \
            const uint4 su = *(const uint4*)(my + (r_) * 16 + h * 8); \
            const uint4 sv = *(const uint4*)(my + (r_) * 16 + h * 8 + 4); \
            unsigned S[8]; \
            S[0] = cvtpk(D[0]  * bflo(su.x), D[1]  * bfhi(su.x)); \
            S[1] = cvtpk(D[2]  * bflo(su.y), D[3]  * bfhi(su.y)); \
            S[2] = cvtpk(D[4]  * bflo(su.z), D[5]  * bfhi(su.z)); \
            S[3] = cvtpk(D[6]  * bflo(su.w), D[7]  * bfhi(su.w)); \
            S[4] = cvtpk(D[8]  * bflo(sv.x), D[9]  * bfhi(sv.x)); \
            S[5] = cvtpk(D[10] * bflo(sv.y), D[11] * bfhi(sv.y)); \
            S[6] = cvtpk(D[12] * bflo(sv.z), D[13] * bfhi(sv.z)); \
            S[7] = cvtpk(D[14] * bflo(sv.w), D[15] * bfhi(sv.w)); \
            f32x16 t_ = __builtin_amdgcn_mfma_f32_32x32x16_bf16(A1v, mk8(&S[0]), Zacc, 0, 0, 0); \
            D = __builtin_amdgcn_mfma_f32_32x32x16_bf16(A2v, mk8(&S[4]), t_, 0, 0, 0); \
        }
        if (clean) {
            #pragma unroll 4
            for (int r = L_CH - 1; r >= 1; --r) STEPF(r);
            if (mbits & 1u) STEPF(0);
        } else {
            for (int r = L_CH - 1; r >= 0; --r)
                if ((mbits >> r) & 1u) STEPF(r);
        }
        #undef STEPF
        ((uint4*)dst)[0] = make_uint4(cvtpk(D[0], D[1]),   cvtpk(D[2], D[3]),
                                      cvtpk(D[4], D[5]),   cvtpk(D[6], D[7]));
        ((uint4*)dst)[1] = make_uint4(cvtpk(D[8], D[9]),   cvtpk(D[10], D[11]),
                                      cvtpk(D[12], D[13]), cvtpk(D[14], D[15]));
    } else {
        unsigned S[8] = {0u, 0u, 0u, 0u, 0u, 0u, 0u, 0u};
        {   // identity in PI-permuted B layout
            const int pn = PIx(n);
            if (((pn >> 3) & 1) == h) {
                const int j = pn & 7;
                const unsigned val = 0x3F80u << (16 * (j & 1));
                if (n < 16) S[j >> 1] |= val; else S[4 + (j >> 1)] |= val;
            }
        }
        #define STEPB(r_) { \
            f32x16 t_ = __builtin_amdgcn_mfma_f32_32x32x16_bf16(A1v, mk8(&S[0]), Zacc, 0, 0, 0); \
            t_ = __builtin_amdgcn_mfma_f32_32x32x16_bf16(A2v, mk8(&S[4]), t_, 0, 0, 0); \
            const uint4 su = *(const uint4*)(my + (r_) * 16 + h * 8); \
            const uint4 sv = *(const uint4*)(my + (r_) * 16 + h * 8 + 4); \
            S[0] = cvtpk(t_[0]  * bflo(su.x), t_[1]  * bfhi(su.x)); \
            S[1] = cvtpk(t_[2]  * bflo(su.y), t_[3]  * bfhi(su.y)); \
            S[2] = cvtpk(t_[4]  * bflo(su.z), t_[5]  * bfhi(su.z)); \
            S[3] = cvtpk(t_[6]  * bflo(su.w), t_[7]  * bfhi(su.w)); \
            S[4] = cvtpk(t_[8]  * bflo(sv.x), t_[9]  * bfhi(sv.x)); \
            S[5] = cvtpk(t_[10] * bflo(sv.y), t_[11] * bfhi(sv.y)); \
            S[6] = cvtpk(t_[12] * bflo(sv.z), t_[13] * bfhi(sv.z)); \
            S[7] = cvtpk(t_[14] * bflo(sv.w), t_[15] * bfhi(sv.w)); \
        }
        if (clean) {
            #pragma unroll 4
            for (int r = 0; r < L_CH; ++r) STEPB(r);
        } else {
            for (int r = 0; r < L_CH; ++r)
                if ((mbits >> r) & 1u) STEPB(r);
        }
        #undef STEPB
        ((uint4*)dst)[0] = make_uint4(S[0], S[1], S[2], S[3]);
        ((uint4*)dst)[1] = make_uint4(S[4], S[5], S[6], S[7]);
    }
}

// two waves per batch: wave0 = alpha over chunks 0..15 (fwd products),
// wave1 = end-vector over chunks 31..16 (transposed products); meet in LDS.
__global__ __launch_bounds__(128) void crf_combine(
    const float* __restrict__ em, const int* __restrict__ tags,
    const float* __restrict__ startT, const float* __restrict__ endT,
    const unsigned* __restrict__ wsf, const float* __restrict__ wsflt,
    float* __restrict__ out)
{
    __shared__ float sm[68];
    const int lane = threadIdx.x & 63;
    const int w = threadIdx.x >> 6;
    const int n = lane & 31, h = lane >> 5;
    const int b = blockIdx.x;

    int idxA[8], idxB[8];
    #pragma unroll
    for (int j = 0; j < 8; ++j) {
        idxA[j] = PIx(8 * h + j);
        idxB[j] = PIx(16 + 8 * h + j);
    }

    float a0 = (w == 0) ? (startT[n] + em[(size_t)b * S_N * T_N + n]) : endT[n];
    float m = a0;
    #pragma unroll
    for (int d = 16; d > 0; d >>= 1) m = fmaxf(m, __shfl_xor(m, d, 32));
    float A = __expf(a0 - m);
    float Lacc = m;
    float ntot = 0.0f;

    const uint4* fb = (const uint4*)(wsf + (size_t)b * C_CH * 512);
    const int c0 = (w == 0) ? 0 : 31;
    const int dc = (w == 0) ? 1 : -1;
    uint4 q0 = fb[c0 * 128 + lane * 2];
    uint4 q1 = fb[c0 * 128 + lane * 2 + 1];

    for (int i = 0; i < 16; ++i) {
        const int c = c0 + i * dc;
        uint4 n0 = q0, n1 = q1;
        if (i + 1 < 16) {
            n0 = fb[(c + dc) * 128 + lane * 2];
            n1 = fb[(c + dc) * 128 + lane * 2 + 1];
        }
        ntot += wsflt[WS_NAPP_OFF + b * C_CH + c];

        float p0 = 0.f, p1 = 0.f, p2 = 0.f, p3 = 0.f;
        p0 = fmaf(__shfl(A, idxA[0], 32), bflo(q0.x), p0);
        p1 = fmaf(__shfl(A, idxA[1], 32), bfhi(q0.x), p1);
        p2 = fmaf(__shfl(A, idxA[2], 32), bflo(q0.y), p2);
        p3 = fmaf(__shfl(A, idxA[3], 32), bfhi(q0.y), p3);
        p0 = fmaf(__shfl(A, idxA[4], 32), bflo(q0.z), p0);
        p1 = fmaf(__shfl(A, idxA[5], 32), bfhi(q0.z), p1);
        p2 = fmaf(__shfl(A, idxA[6], 32), bflo(q0.w), p2);
        p3 = fmaf(__shfl(A, idxA[7], 32), bfhi(q0.w), p3);
        p0 = fmaf(__shfl(A, idxB[0], 32), bflo(q1.x), p0);
        p1 = fmaf(__shfl(A, idxB[1], 32), bfhi(q1.x), p1);
        p2 = fmaf(__shfl(A, idxB[2], 32), bflo(q1.y), p2);
        p3 = fmaf(__shfl(A, idxB[3], 32), bfhi(q1.y), p3);
        p0 = fmaf(__shfl(A, idxB[4], 32), bflo(q1.z), p0);
        p1 = fmaf(__shfl(A, idxB[5], 32), bfhi(q1.z), p1);
        p2 = fmaf(__shfl(A, idxB[6], 32), bflo(q1.w), p2);
        p3 = fmaf(__shfl(A, idxB[7], 32), bfhi(q1.w), p3);
        float part = (p0 + p1) + (p2 + p3);
        part += __shfl_xor(part, 32);           // fold half-wave partials

        float mm = part;
        #pragma unroll
        for (int d = 16; d > 0; d >>= 1) mm = fmaxf(mm, __shfl_xor(mm, d, 32));
        A = part / mm;
        Lacc += __logf(mm);
        q0 = n0; q1 = n1;
    }

    if (h == 0) sm[w * 32 + n] = A;
    if (lane == 0) { sm[64 + w] = Lacc; sm[66 + w] = ntot; }
    __syncthreads();

    if (threadIdx.x < 32) {
        float v = sm[threadIdx.x] * sm[32 + threadIdx.x];
        #pragma unroll
        for (int d = 16; d > 0; d >>= 1) v += __shfl_xor(v, d, 32);
        if (threadIdx.x == 0) {
            const float part = sm[64] + sm[65] + __logf(v) + (sm[66] + sm[67]) * SCALE_LOG;
            const int len = (int)(wsflt[WS_MSUM_OFF + b] + 0.5f);
            const int lt  = tags[b * S_N + len - 1];
            atomicAdd(out, part - endT[lt] - wsflt[WS_SCORE_OFF + b]);
        }
    }
}

extern "C" void kernel_launch(void* const* d_in, const int* in_sizes, int n_in,
                              void* d_out, int out_size, void* d_ws, size_t ws_size,
                              hipStream_t stream) {
    const float* em     = (const float*)d_in[0];
    const int*   tags   = (const int*)  d_in[1];
    const float* mask   = (const float*)d_in[2];
    const float* trans  = (const float*)d_in[3];
    const float* startT = (const float*)d_in[4];
    const float* endT   = (const float*)d_in[5];
    float* out = (float*)d_out;

    unsigned* wsf   = (unsigned*)d_ws;
    float*    wsflt = (float*)d_ws;

    hipMemsetAsync(out, 0, sizeof(float), stream);
    hipMemsetAsync((char*)d_ws + WS_MSUM_OFF * 4, 0, 4096, stream);

    // 512 batches x 32 chunks, 1 wave per chunk; 8 KiB LDS, 8 blocks/CU
    hipLaunchKernelGGL(crf_chunk, dim3(4096), dim3(256), 0, stream,
                       em, tags, mask, trans, startT, wsf, wsflt);
    hipLaunchKernelGGL(crf_combine, dim3(512), dim3(128), 0, stream,
                       em, tags, startT, endT, wsf, wsflt, out);
}

// Round 7
// 179.451 us; speedup vs baseline: 1.0506x; 1.0506x over previous
//
#include <hip/hip_runtime.h>

// CRF NLL on MI355X — round 7: ILP-4 chains x TLP-4 blocks/CU, prep'd A-frags.
//
// partition_b = log( a0 . (prod_t M_t) . exp(end) ),  M_t = ET . diag(ee_t).
// 32 chunks x 32 matrices per batch. Each wave runs FOUR interleaved chunk
// chains (r5's best per-step structure); blocks of 4 waves stage 16 chunks in
// 32 KiB LDS; launch_bounds(256,4) -> 4 blocks/CU resident (1024 blocks total,
// exactly one residency generation), 16 chains/SIMD. The per-wave scattered
// exp(trans) gathers that regressed r6 are hoisted into a one-block prep
// kernel; chunk waves load packed A-fragments with 2 coalesced dwordx4.
// PI-aligned step (C/D reg order == next B operand order, zero cross-lane)
// verbatim from r5/r6. Path score fused. 2^-7/matrix scaling (exact).
//
// ws (dwords): [0, FRAG) fragments (512 per (b,c));
//   FRAG+0..511 msum[b]; +512..1023 score[b]; +1024.. A-frag (512);
//   +1536.. napp[b*32+c] (16384).

typedef __attribute__((ext_vector_type(8)))  short    short8;
typedef __attribute__((ext_vector_type(16))) float    f32x16;
typedef __attribute__((ext_vector_type(4)))  unsigned uint4v;

#define S_N 1024
#define T_N 32
#define B_N 512
#define L_CH 32
#define C_CH 32
#define SCALE_MUL 0.0078125f           // 2^-7 folded into ee
#define SCALE_LOG 4.852030263919617f   // 7*ln2 per applied matrix

#define WS_FRAG_DW ((size_t)B_N * C_CH * 512)          // 32 MiB
#define WS_MSUM_OFF (WS_FRAG_DW)
#define WS_SCORE_OFF (WS_FRAG_DW + 512)
#define WS_A_OFF (WS_FRAG_DW + 1024)
#define WS_NAPP_OFF (WS_FRAG_DW + 1536)

#if __has_builtin(__builtin_amdgcn_cvt_pk_bf16_f32)
typedef __attribute__((ext_vector_type(2))) __bf16 bf16x2;
__device__ __forceinline__ unsigned cvtpk(float lo, float hi) {
    return __builtin_bit_cast(unsigned, __builtin_amdgcn_cvt_pk_bf16_f32(lo, hi));
}
#else
__device__ __forceinline__ unsigned cvtpk(float lo, float hi) {
    const unsigned a = __float_as_uint(lo) + 0x8000u;
    const unsigned b = __float_as_uint(hi) + 0x8000u;
    return __builtin_amdgcn_perm(b, a, 0x07060302u);
}
#endif

__device__ __forceinline__ short8 mk8(const unsigned* a) {
    uint4v u = {a[0], a[1], a[2], a[3]};
    return __builtin_bit_cast(short8, u);
}
__device__ __forceinline__ float bflo(unsigned u) { return __uint_as_float(u << 16); }
__device__ __forceinline__ float bfhi(unsigned u) { return __uint_as_float(u & 0xFFFF0000u); }
// PI: involution swapping rows 4-7<->8-11 and 20-23<->24-27
__device__ __forceinline__ int PIx(int x) { return (x & ~12) | ((x & 4) << 1) | ((x & 8) >> 1); }

// one 64-lane block: packed bf16 A-fragments of exp(trans), PI-permuted cols
__global__ __launch_bounds__(64) void crf_prep(
    const float* __restrict__ trans, unsigned* __restrict__ wsf)
{
    const int lane = threadIdx.x;
    const int n = lane & 31, h = lane >> 5;
    unsigned A1[4], A2[4];
    #pragma unroll
    for (int j = 0; j < 4; ++j) {
        const int k1 = PIx(8 * h + 2 * j);
        const int k2 = PIx(16 + 8 * h + 2 * j);
        A1[j] = cvtpk(__expf(trans[n * 32 + k1]), __expf(trans[n * 32 + k1 + 1]));
        A2[j] = cvtpk(__expf(trans[n * 32 + k2]), __expf(trans[n * 32 + k2 + 1]));
    }
    unsigned* dst = wsf + WS_A_OFF + lane * 8;
    ((uint4*)dst)[0] = make_uint4(A1[0], A1[1], A1[2], A1[3]);
    ((uint4*)dst)[1] = make_uint4(A2[0], A2[1], A2[2], A2[3]);
}

__global__ __launch_bounds__(256, 4) void crf_chunk(
    const float* __restrict__ em, const int* __restrict__ tags,
    const float* __restrict__ mask, const float* __restrict__ trans,
    const float* __restrict__ startT, unsigned* __restrict__ wsf,
    float* __restrict__ wsflt)
{
    __shared__ unsigned elds[16][512];     // 32 KiB: 16 chunks x 2 KiB
    const int wib  = threadIdx.x >> 6;
    const int lane = threadIdx.x & 63;
    const int n    = lane & 31;
    const int h    = lane >> 5;
    const int b    = blockIdx.x >> 1;
    const int half = blockIdx.x & 1;
    const int c0   = half * 16 + wib * 4;  // this wave's first chunk

    // ---- stage packed scales for 4 chunks (exp once per element) ----
    #pragma unroll
    for (int q = 0; q < 4; ++q) {
        const float* eq = em + ((size_t)b * S_N + (c0 + q) * L_CH) * T_N;
        unsigned* mq = elds[wib * 4 + q];
        #pragma unroll
        for (int i = 0; i < 8; ++i) {
            const int flat = i * 64 + lane;
            const int r = flat >> 4, m = flat & 15;
            const int base = ((m & 4) << 2) + ((m & 2) << 2) + ((m & 1) << 1) + ((m >> 3) << 2);
            const float2 v = *(const float2*)(eq + r * 32 + base);
            mq[r * 16 + m] = cvtpk(__expf(v.x) * SCALE_MUL, __expf(v.y) * SCALE_MUL);
        }
    }

    // ---- mask ballots (4 chunks) + fused path-score partial ----
    unsigned mb_[4];
    {
        float vacc = 0.f, macc = 0.f;
        #pragma unroll
        for (int q2 = 0; q2 < 2; ++q2) {
            const int s  = c0 * L_CH + q2 * 64 + lane;
            const float mv = mask[b * S_N + s];
            const unsigned long long mb = __ballot(mv != 0.0f);
            mb_[2 * q2]     = (unsigned)mb;
            mb_[2 * q2 + 1] = (unsigned)(mb >> 32);
            const int tc = tags[b * S_N + s];
            int tp = __shfl_up(tc, 1, 64);
            float val;
            if (lane == 0) {
                if (s == 0) {
                    val = startT[tc] + em[(size_t)b * S_N * T_N + tc];
                } else {
                    tp = tags[b * S_N + s - 1];
                    val = mv * (em[((size_t)b * S_N + s) * T_N + tc] + trans[tp * 32 + tc]);
                }
            } else {
                val = mv * (em[((size_t)b * S_N + s) * T_N + tc] + trans[tp * 32 + tc]);
            }
            vacc += val; macc += mv;
        }
        if (c0 == 0) mb_[0] &= ~1u;        // t=0 has no transition matrix
        #pragma unroll
        for (int d = 32; d > 0; d >>= 1) {
            vacc += __shfl_xor(vacc, d, 64);
            macc += __shfl_xor(macc, d, 64);
        }
        if (lane == 0) {
            atomicAdd(&wsflt[WS_SCORE_OFF + b], vacc);
            atomicAdd(&wsflt[WS_MSUM_OFF + b], macc);
            #pragma unroll
            for (int q = 0; q < 4; ++q)
                wsflt[WS_NAPP_OFF + b * C_CH + c0 + q] = (float)__popc(mb_[q]);
        }
    }

    // ---- loop-invariant A fragments from prep (2 coalesced dwordx4) ----
    const uint4 ua = ((const uint4*)(wsf + WS_A_OFF))[lane * 2];
    const uint4 ub = ((const uint4*)(wsf + WS_A_OFF))[lane * 2 + 1];
    const short8 A1v = mk8((const unsigned*)&ua);
    const short8 A2v = mk8((const unsigned*)&ub);
    const f32x16 Zacc = {};

    // ---- 4 chain states: identity in C layout ----
    f32x16 D0, D1, D2, D3;
    #pragma unroll
    for (int i = 0; i < 16; ++i) {
        const int row = (i & 3) + 8 * (i >> 2) + 4 * h;
        const float v = (row == n) ? 1.0f : 0.0f;
        D0[i] = v; D1[i] = v; D2[i] = v; D3[i] = v;
    }

    const unsigned* m0 = elds[wib * 4];
    const unsigned* m1 = elds[wib * 4 + 1];
    const unsigned* m2 = elds[wib * 4 + 2];
    const unsigned* m3 = elds[wib * 4 + 3];

    #define STEP(D, mq, r_) { \
        const uint4 su = *(const uint4*)((mq) + (r_) * 16 + h * 8); \
        const uint4 sv = *(const uint4*)((mq) + (r_) * 16 + h * 8 + 4); \
        unsigned S[8]; \
        S[0] = cvtpk(D[0]  * bflo(su.x), D[1]  * bfhi(su.x)); \
        S[1] = cvtpk(D[2]  * bflo(su.y), D[3]  * bfhi(su.y)); \
        S[2] = cvtpk(D[4]  * bflo(su.z), D[5]  * bfhi(su.z)); \
        S[3] = cvtpk(D[6]  * bflo(su.w), D[7]  * bfhi(su.w)); \
        S[4] = cvtpk(D[8]  * bflo(sv.x), D[9]  * bfhi(sv.x)); \
        S[5] = cvtpk(D[10] * bflo(sv.y), D[11] * bfhi(sv.y)); \
        S[6] = cvtpk(D[12] * bflo(sv.z), D[13] * bfhi(sv.z)); \
        S[7] = cvtpk(D[14] * bflo(sv.w), D[15] * bfhi(sv.w)); \
        f32x16 t_ = __builtin_amdgcn_mfma_f32_32x32x16_bf16(A1v, mk8(&S[0]), Zacc, 0, 0, 0); \
        D = __builtin_amdgcn_mfma_f32_32x32x16_bf16(A2v, mk8(&S[4]), t_, 0, 0, 0); \
    }

    const bool allclean =
        ((mb_[0] | (c0 == 0 ? 1u : 0u)) == 0xFFFFFFFFu) &&
        (mb_[1] == 0xFFFFFFFFu) && (mb_[2] == 0xFFFFFFFFu) && (mb_[3] == 0xFFFFFFFFu);

    if (allclean) {
        #pragma unroll 2
        for (int r = L_CH - 1; r >= 1; --r) {
            STEP(D0, m0, r); STEP(D1, m1, r); STEP(D2, m2, r); STEP(D3, m3, r);
        }
        if (mb_[0] & 1u) STEP(D0, m0, 0);   // c0==0 has bit0 cleared
        if (mb_[1] & 1u) STEP(D1, m1, 0);
        if (mb_[2] & 1u) STEP(D2, m2, 0);
        if (mb_[3] & 1u) STEP(D3, m3, 0);
    } else {
        for (int r = L_CH - 1; r >= 0; --r) {
            if ((mb_[0] >> r) & 1u) STEP(D0, m0, r);
            if ((mb_[1] >> r) & 1u) STEP(D1, m1, r);
            if ((mb_[2] >> r) & 1u) STEP(D2, m2, r);
            if ((mb_[3] >> r) & 1u) STEP(D3, m3, r);
        }
    }
    #undef STEP

    #define STORE(D, q_) { \
        unsigned* dst = wsf + ((size_t)(b * C_CH + c0 + (q_)) * 64 + lane) * 8; \
        ((uint4*)dst)[0] = make_uint4(cvtpk(D[0], D[1]),   cvtpk(D[2], D[3]), \
                                      cvtpk(D[4], D[5]),   cvtpk(D[6], D[7])); \
        ((uint4*)dst)[1] = make_uint4(cvtpk(D[8], D[9]),   cvtpk(D[10], D[11]), \
                                      cvtpk(D[12], D[13]), cvtpk(D[14], D[15])); \
    }
    STORE(D0, 0) STORE(D1, 1) STORE(D2, 2) STORE(D3, 3)
    #undef STORE
}

// one wave per batch: 32-step alpha row-vector chain over the chunk products
__global__ __launch_bounds__(256) void crf_combine(
    const float* __restrict__ em, const int* __restrict__ tags,
    const float* __restrict__ startT, const float* __restrict__ endT,
    const unsigned* __restrict__ wsf, const float* __restrict__ wsflt,
    float* __restrict__ out)
{
    const int lane = threadIdx.x & 63;
    const int n = lane & 31, h = lane >> 5;
    const int b = blockIdx.x * 4 + (threadIdx.x >> 6);

    int idxA[8], idxB[8];
    #pragma unroll
    for (int j = 0; j < 8; ++j) {
        idxA[j] = PIx(8 * h + j);
        idxB[j] = PIx(16 + 8 * h + j);
    }

    float a0 = startT[n] + em[(size_t)b * S_N * T_N + n];
    float m = a0;
    #pragma unroll
    for (int d = 16; d > 0; d >>= 1) m = fmaxf(m, __shfl_xor(m, d, 32));
    float A = __expf(a0 - m);
    float Lacc = m;
    float ntot = (lane < 32) ? wsflt[WS_NAPP_OFF + b * C_CH + lane] : 0.0f;

    const uint4* fb = (const uint4*)(wsf + (size_t)b * C_CH * 512);
    uint4 q0 = fb[lane * 2];
    uint4 q1 = fb[lane * 2 + 1];

    for (int c = 0; c < C_CH; ++c) {
        uint4 n0 = q0, n1 = q1;
        if (c + 1 < C_CH) {                      // prefetch next chunk's fragment
            n0 = fb[(c + 1) * 128 + lane * 2];
            n1 = fb[(c + 1) * 128 + lane * 2 + 1];
        }

        float p0 = 0.f, p1 = 0.f, p2 = 0.f, p3 = 0.f;
        p0 = fmaf(__shfl(A, idxA[0], 32), bflo(q0.x), p0);
        p1 = fmaf(__shfl(A, idxA[1], 32), bfhi(q0.x), p1);
        p2 = fmaf(__shfl(A, idxA[2], 32), bflo(q0.y), p2);
        p3 = fmaf(__shfl(A, idxA[3], 32), bfhi(q0.y), p3);
        p0 = fmaf(__shfl(A, idxA[4], 32), bflo(q0.z), p0);
        p1 = fmaf(__shfl(A, idxA[5], 32), bfhi(q0.z), p1);
        p2 = fmaf(__shfl(A, idxA[6], 32), bflo(q0.w), p2);
        p3 = fmaf(__shfl(A, idxA[7], 32), bfhi(q0.w), p3);
        p0 = fmaf(__shfl(A, idxB[0], 32), bflo(q1.x), p0);
        p1 = fmaf(__shfl(A, idxB[1], 32), bfhi(q1.x), p1);
        p2 = fmaf(__shfl(A, idxB[2], 32), bflo(q1.y), p2);
        p3 = fmaf(__shfl(A, idxB[3], 32), bfhi(q1.y), p3);
        p0 = fmaf(__shfl(A, idxB[4], 32), bflo(q1.z), p0);
        p1 = fmaf(__shfl(A, idxB[5], 32), bfhi(q1.z), p1);
        p2 = fmaf(__shfl(A, idxB[6], 32), bflo(q1.w), p2);
        p3 = fmaf(__shfl(A, idxB[7], 32), bfhi(q1.w), p3);
        float part = (p0 + p1) + (p2 + p3);
        part += __shfl_xor(part, 32);           // fold half-wave partials

        float mm = part;
        #pragma unroll
        for (int d = 16; d > 0; d >>= 1) mm = fmaxf(mm, __shfl_xor(mm, d, 32));
        A = part / mm;
        Lacc += __logf(mm);
        q0 = n0; q1 = n1;
    }

    float v = A * __expf(endT[n]);
    #pragma unroll
    for (int d = 16; d > 0; d >>= 1) {
        v    += __shfl_xor(v, d, 32);
        ntot += __shfl_xor(ntot, d, 32);
    }
    if (lane == 0) {
        const int len = (int)(wsflt[WS_MSUM_OFF + b] + 0.5f);
        const int lt  = tags[b * S_N + len - 1];
        const float res = Lacc + __logf(v) + ntot * SCALE_LOG
                          - endT[lt] - wsflt[WS_SCORE_OFF + b];
        atomicAdd(out, res);
    }
}

extern "C" void kernel_launch(void* const* d_in, const int* in_sizes, int n_in,
                              void* d_out, int out_size, void* d_ws, size_t ws_size,
                              hipStream_t stream) {
    const float* em     = (const float*)d_in[0];
    const int*   tags   = (const int*)  d_in[1];
    const float* mask   = (const float*)d_in[2];
    const float* trans  = (const float*)d_in[3];
    const float* startT = (const float*)d_in[4];
    const float* endT   = (const float*)d_in[5];
    float* out = (float*)d_out;

    unsigned* wsf   = (unsigned*)d_ws;
    float*    wsflt = (float*)d_ws;

    hipMemsetAsync(out, 0, sizeof(float), stream);
    hipMemsetAsync((char*)d_ws + WS_MSUM_OFF * 4, 0, 4096, stream);

    hipLaunchKernelGGL(crf_prep, dim3(1), dim3(64), 0, stream, trans, wsf);
    // 512 batches x 2 half-batches; 4 waves x 4 chains; 32 KiB LDS, 4 blocks/CU
    hipLaunchKernelGGL(crf_chunk, dim3(1024), dim3(256), 0, stream,
                       em, tags, mask, trans, startT, wsf, wsflt);
    hipLaunchKernelGGL(crf_combine, dim3(128), dim3(256), 0, stream,
                       em, tags, startT, endT, wsf, wsflt, out);
}